// Round 9
// baseline (327.825 us; speedup 1.0000x reference)
//
#include <hip/hip_runtime.h>
#include <hip/hip_bf16.h>
#include <stdint.h>
#include <math.h>

#define IN_DIM 128
#define H_HEADS 8
#define HD 16

typedef __attribute__((ext_vector_type(8))) short bf16x8;
typedef __attribute__((ext_vector_type(4))) float f32x4;

__device__ __forceinline__ unsigned short f2bf(float f) {
    __hip_bfloat16 h = __float2bfloat16(f);     // RNE
    return reinterpret_cast<unsigned short&>(h);
}
__device__ __forceinline__ float bf2f(unsigned short h) {
    return __uint_as_float(((unsigned int)h) << 16);
}

__device__ __forceinline__ void split_f8(const float4 f0, const float4 f1,
                                         bf16x8& h8, bf16x8& l8) {
    float ff[8] = {f0.x, f0.y, f0.z, f0.w, f1.x, f1.y, f1.z, f1.w};
    union { bf16x8 v; unsigned short u[8]; } H, L;
#pragma unroll
    for (int j = 0; j < 8; ++j) {
        H.u[j] = f2bf(ff[j]);
        L.u[j] = f2bf(ff[j] - bf2f(H.u[j]));
    }
    h8 = H.v; l8 = L.v;
}

// stage one 32KB B matrix ([c][k] 128x128 shorts) into LDS, XOR-swizzled 16B cols
__device__ __forceinline__ void stage_B(const unsigned short* __restrict__ src,
                                        unsigned short* __restrict__ lds, int t)
{
#pragma unroll
    for (int j = 0; j < 8; ++j) {
        int idx16 = t + j * 256;
        int c = idx16 >> 4, kcol = idx16 & 15;
        uint4 v = *reinterpret_cast<const uint4*>(src + (size_t)c * 128 + kcol * 8);
        *reinterpret_cast<uint4*>(lds + c * 128 + ((kcol ^ (c & 15)) * 8)) = v;
    }
}
__device__ __forceinline__ bf16x8 read_B(const unsigned short* __restrict__ lds,
                                         int c, int kcol)
{
    return *reinterpret_cast<const bf16x8*>(lds + c * 128 + ((kcol ^ (c & 15)) * 8));
}

// ---------- prep (5 blocks): W transpose/split + biases; rest: degree histogram ----------
__global__ __launch_bounds__(256)
void prep_count_kernel(const float* __restrict__ Wq, const float* __restrict__ Wk,
                       const float* __restrict__ Wv, const float* __restrict__ Wsk,
                       const float* __restrict__ Wo,
                       const float* __restrict__ bq, const float* __restrict__ bk,
                       const float* __restrict__ bv, const float* __restrict__ bsk,
                       unsigned short* __restrict__ WtH, unsigned short* __restrict__ WtL,
                       float* __restrict__ bias_cat,
                       const int* __restrict__ ei, int* __restrict__ deg, int E)
{
    const int b = blockIdx.x;
    const int t = threadIdx.x;
    if (b >= 5) {
        int e = (b - 5) * 256 + t;
        if (e < E) atomicAdd(&deg[ei[E + e]], 1);
        return;
    }
    const int p = b;
    const float* src = (p == 0) ? Wq : (p == 1) ? Wk : (p == 2) ? Wv : (p == 3) ? Wsk : Wo;
    unsigned short* dh = WtH + (size_t)p * 16384;
    unsigned short* dl = WtL + (size_t)p * 16384;
#pragma unroll
    for (int j = 0; j < 64; ++j) {
        int o = t + j * 256;            // o = c*128 + k
        int c = o >> 7, k = o & 127;
        float v;
        if (p < 4) {
            int h = c >> 4, d = c & 15;
            v = src[(size_t)h * 2048 + (size_t)k * 16 + d];
        } else {
            v = src[(size_t)k * 128 + c];
        }
        unsigned short hi = f2bf(v);
        unsigned short lo = f2bf(v - bf2f(hi));
        dh[o] = hi; dl[o] = lo;
    }
    if (p < 4 && t < 128) {
        const float* bb = (p == 0) ? bq : (p == 1) ? bk : (p == 2) ? bv : bsk;
        bias_cat[p * 128 + t] = bb[t];
    }
}

// ---------- proj GEMM: 2 projections per block (A-frags loaded once) ----------
// grid (ceil(N/64), 2); blockIdx.y=0 -> {q,k}, 1 -> {v,skip}.
__global__ __launch_bounds__(256)
void gemm_proj_kernel(const float* __restrict__ A,
                      const unsigned short* __restrict__ WtH_base,
                      const unsigned short* __restrict__ WtL_base,
                      const float* __restrict__ bias_cat,
                      float* __restrict__ qout, float* __restrict__ skipout,
                      unsigned short* __restrict__ kvout, int N)
{
    __shared__ unsigned short Bs[16384];
    const int t = threadIdx.x;
    const int lane = t & 63;
    const int w = t >> 6;
    const int lr = lane & 15;
    const int lk = lane >> 4;
    const int pr = blockIdx.y;              // 0:{q,k} 1:{v,skip}
    const int brow0 = blockIdx.x * 64 + w * 16;
    const int arow = min(brow0 + lr, N - 1);
    const float* ap = A + (size_t)arow * 128;

    bf16x8 ah[4], al[4];
#pragma unroll
    for (int ks = 0; ks < 4; ++ks) {
        float4 f0 = *reinterpret_cast<const float4*>(ap + ks * 32 + lk * 8);
        float4 f1 = *reinterpret_cast<const float4*>(ap + ks * 32 + lk * 8 + 4);
        split_f8(f0, f1, ah[ks], al[ks]);
    }

    for (int pp = 0; pp < 2; ++pp) {
        const int p = pr * 2 + pp;          // 0=q 1=k 2=v 3=skip
        f32x4 acc[8];
#pragma unroll
        for (int ni = 0; ni < 8; ++ni) acc[ni] = (f32x4){0.f, 0.f, 0.f, 0.f};

        __syncthreads();                    // protect Bs from previous readers
        stage_B(WtH_base + (size_t)p * 16384, Bs, t);
        __syncthreads();
#pragma unroll
        for (int ks = 0; ks < 4; ++ks)
#pragma unroll
            for (int ni = 0; ni < 8; ++ni) {
                bf16x8 bh = read_B(Bs, ni * 16 + lr, ks * 4 + lk);
                acc[ni] = __builtin_amdgcn_mfma_f32_16x16x32_bf16(ah[ks], bh, acc[ni], 0, 0, 0);
                acc[ni] = __builtin_amdgcn_mfma_f32_16x16x32_bf16(al[ks], bh, acc[ni], 0, 0, 0);
            }
        __syncthreads();
        stage_B(WtL_base + (size_t)p * 16384, Bs, t);
        __syncthreads();
#pragma unroll
        for (int ks = 0; ks < 4; ++ks)
#pragma unroll
            for (int ni = 0; ni < 8; ++ni) {
                bf16x8 bl = read_B(Bs, ni * 16 + lr, ks * 4 + lk);
                acc[ni] = __builtin_amdgcn_mfma_f32_16x16x32_bf16(ah[ks], bl, acc[ni], 0, 0, 0);
            }

        const float* bias = bias_cat + p * 128;
        if (p == 0 || p == 3) {
            float* outp = (p == 0) ? qout : skipout;
#pragma unroll
            for (int ni = 0; ni < 8; ++ni) {
                int col = ni * 16 + lr;
                float bc = bias[col];
#pragma unroll
                for (int r = 0; r < 4; ++r) {
                    int gr = brow0 + lk * 4 + r;
                    if (gr < N) outp[(size_t)gr * 128 + col] = acc[ni][r] + bc;
                }
            }
        } else {
            unsigned int* kvu = (unsigned int*)kvout;
            const int slot = (p == 1) ? 0 : 1;
#pragma unroll
            for (int ni = 0; ni < 8; ++ni) {
                int col = ni * 16 + lr;
                float bc = bias[col];
#pragma unroll
                for (int r = 0; r < 4; ++r) {
                    unsigned int s = f2bf(acc[ni][r] + bc);
                    unsigned int o = __shfl_xor((int)s, 1);
                    int gr = brow0 + lk * 4 + r;
                    if (((lr & 1) == 0) && gr < N)
                        kvu[(size_t)gr * 128 + 2 * (col >> 1) + slot] = s | (o << 16);
                }
            }
        }
    }
}

// ---------- out GEMM + residual + fused LayerNorm (64-row blocks, in-wave LN) ----------
__global__ __launch_bounds__(256)
void gemm_out_ln_kernel(const float* __restrict__ A,
                        const unsigned short* __restrict__ BtH_t,
                        const unsigned short* __restrict__ BtL_t,
                        const float* __restrict__ bo,
                        const float* __restrict__ res,
                        const float* __restrict__ gamma,
                        const float* __restrict__ beta,
                        float* __restrict__ out, int N)
{
    __shared__ unsigned short Bs[16384];
    const int t = threadIdx.x;
    const int lane = t & 63;
    const int w = t >> 6;
    const int lr = lane & 15;
    const int lk = lane >> 4;
    const int brow0 = blockIdx.x * 64 + w * 16;
    const int arow = min(brow0 + lr, N - 1);
    const float* ap = A + (size_t)arow * 128;

    bf16x8 ah[4], al[4];
#pragma unroll
    for (int ks = 0; ks < 4; ++ks) {
        float4 f0 = *reinterpret_cast<const float4*>(ap + ks * 32 + lk * 8);
        float4 f1 = *reinterpret_cast<const float4*>(ap + ks * 32 + lk * 8 + 4);
        split_f8(f0, f1, ah[ks], al[ks]);
    }

    f32x4 acc[8];
#pragma unroll
    for (int ni = 0; ni < 8; ++ni) acc[ni] = (f32x4){0.f, 0.f, 0.f, 0.f};

    stage_B(BtH_t, Bs, t);
    __syncthreads();
#pragma unroll
    for (int ks = 0; ks < 4; ++ks)
#pragma unroll
        for (int ni = 0; ni < 8; ++ni) {
            bf16x8 bh = read_B(Bs, ni * 16 + lr, ks * 4 + lk);
            acc[ni] = __builtin_amdgcn_mfma_f32_16x16x32_bf16(ah[ks], bh, acc[ni], 0, 0, 0);
            acc[ni] = __builtin_amdgcn_mfma_f32_16x16x32_bf16(al[ks], bh, acc[ni], 0, 0, 0);
        }
    __syncthreads();
    stage_B(BtL_t, Bs, t);
    __syncthreads();
#pragma unroll
    for (int ks = 0; ks < 4; ++ks)
#pragma unroll
        for (int ni = 0; ni < 8; ++ni) {
            bf16x8 bl = read_B(Bs, ni * 16 + lr, ks * 4 + lk);
            acc[ni] = __builtin_amdgcn_mfma_f32_16x16x32_bf16(ah[ks], bl, acc[ni], 0, 0, 0);
        }

#pragma unroll
    for (int ni = 0; ni < 8; ++ni) {
        int col = ni * 16 + lr;
        float bc = bo[col];
#pragma unroll
        for (int r = 0; r < 4; ++r) {
            int gr = brow0 + lk * 4 + r;
            float rv = (gr < N) ? res[(size_t)gr * 128 + col] : 0.f;
            acc[ni][r] += bc + rv;
        }
    }
#pragma unroll
    for (int r = 0; r < 4; ++r) {
        float s = 0.f, sq = 0.f;
#pragma unroll
        for (int ni = 0; ni < 8; ++ni) { float v = acc[ni][r]; s += v; sq += v * v; }
#pragma unroll
        for (int mk = 1; mk < 16; mk <<= 1) {
            s  += __shfl_xor(s, mk);
            sq += __shfl_xor(sq, mk);
        }
        float mean = s * (1.0f / 128.0f);
        float var  = sq * (1.0f / 128.0f) - mean * mean;
        float inv  = rsqrtf(var + 1e-5f);
        int gr = brow0 + lk * 4 + r;
        if (gr < N) {
#pragma unroll
            for (int ni = 0; ni < 8; ++ni) {
                int col = ni * 16 + lr;
                out[(size_t)gr * 128 + col] =
                    (acc[ni][r] - mean) * inv * gamma[col] + beta[col];
            }
        }
    }
}

// ---------------- parallel scan: 3 kernels ----------------
__global__ __launch_bounds__(1024)
void scan_part1(const int* __restrict__ deg, int* __restrict__ offs,
                int* __restrict__ csums, int N)
{
    __shared__ int wsum[16];
    const int t = threadIdx.x;
    const int lane = t & 63, wid = t >> 6;
    const int idx = blockIdx.x * 4096 + t * 4;
    int v[4];
#pragma unroll
    for (int j = 0; j < 4; ++j) { int i = idx + j; v[j] = (i < N) ? deg[i] : 0; }
    int ls = v[0] + v[1] + v[2] + v[3];
    int inc = ls;
#pragma unroll
    for (int off = 1; off < 64; off <<= 1) {
        int y = __shfl_up(inc, off);
        if (lane >= off) inc += y;
    }
    if (lane == 63) wsum[wid] = inc;
    __syncthreads();
    if (t < 16) {
        int winc = wsum[t];
        for (int off = 1; off < 16; off <<= 1) {
            int y = __shfl_up(winc, off);
            if (t >= off) winc += y;
        }
        wsum[t] = winc;
    }
    __syncthreads();
    int wexcl = (wid == 0) ? 0 : wsum[wid - 1];
    int texcl = wexcl + (inc - ls);
    int pre = 0;
#pragma unroll
    for (int j = 0; j < 4; ++j) {
        int i = idx + j;
        if (i < N) offs[i] = texcl + pre;
        pre += v[j];
    }
    if (t == 0) csums[blockIdx.x] = wsum[15];
}

__global__ void scan_part2(int* __restrict__ csums, int nc,
                           int* __restrict__ offs, int N)
{
    const int t = threadIdx.x;          // 64 threads
    int v = (t < nc) ? csums[t] : 0;
    int inc = v;
#pragma unroll
    for (int off = 1; off < 64; off <<= 1) {
        int y = __shfl_up(inc, off);
        if (t >= off) inc += y;
    }
    if (t < nc) csums[t] = inc - v;     // exclusive
    int total = __shfl(inc, nc - 1);
    if (t == 0) offs[N] = total;
}

__global__ __launch_bounds__(1024)
void scan_part3(int* __restrict__ offs, const int* __restrict__ csums,
                int* __restrict__ cursor, int N)
{
    const int coff = csums[blockIdx.x];
    const int idx = blockIdx.x * 4096 + threadIdx.x * 4;
#pragma unroll
    for (int j = 0; j < 4; ++j) {
        int i = idx + j;
        if (i < N) { int val = offs[i] + coff; offs[i] = val; cursor[i] = val; }
    }
}

// ---------------- scatter edges into CSR (packed int2 {src, ea}) ----------------
__global__ void scatter_kernel(const int* __restrict__ ei, const float* __restrict__ ea,
                               int* __restrict__ cursor, int2* __restrict__ csr, int E)
{
    int e = blockIdx.x * 256 + threadIdx.x;
    if (e < E) {
        int s = ei[e], d = ei[E + e];
        int pos = atomicAdd(&cursor[d], 1);
        csr[pos] = make_int2(s, __float_as_int(ea[e]));
    }
}

// ---------------- per-node online-softmax attention + aggregation ----------------
// wave per node, FOUR 16-lane quarters with independent edge streams.
// Quarter: 8 heads x 2 lanes; lane covers 8 dims (32B of the 512B kv row).
// Defer-max (THR=8); We-term factored out (sWE); single shfl per edge dot.
__global__ __launch_bounds__(256)
void agg_kernel(const float* __restrict__ qb, const float* __restrict__ sb,
                const unsigned short* __restrict__ kvb,
                const int* __restrict__ offs, const int2* __restrict__ csr,
                const float* __restrict__ We, float* __restrict__ heads_cat, int N)
{
    const int lane = threadIdx.x & 63;
    const int node = blockIdx.x * 4 + (threadIdx.x >> 6);
    if (node >= N) return;
    const int q16  = lane & 15;
    const int quad = lane >> 4;

    const float4 qa = *reinterpret_cast<const float4*>(qb + (size_t)node * 128 + 8 * q16);
    const float4 qc = *reinterpret_cast<const float4*>(qb + (size_t)node * 128 + 8 * q16 + 4);
    const float4 wa = *reinterpret_cast<const float4*>(We + 8 * q16);
    const float4 wc = *reinterpret_cast<const float4*>(We + 8 * q16 + 4);

    float qwe = qa.x * wa.x + qa.y * wa.y + qa.z * wa.z + qa.w * wa.w
              + qc.x * wc.x + qc.y * wc.y + qc.z * wc.z + qc.w * wc.w;
    qwe += __shfl_xor(qwe, 1);

    const int e0 = offs[node];
    const int cnt = offs[node + 1] - e0;
    const int myCnt = (cnt > quad) ? ((cnt - quad + 3) >> 2) : 0;
    const int2* cp = csr + e0 + quad;
    const unsigned int* kvu = (const unsigned int*)kvb;

    float m = -__builtin_huge_valf();
    float s = 0.f, sWE = 0.f;
    float a0 = 0.f, a1 = 0.f, a2 = 0.f, a3 = 0.f;
    float a4 = 0.f, a5 = 0.f, a6 = 0.f, a7 = 0.f;

#define KVG(ec, ga, gb) do { \
    const uint4* p_ = reinterpret_cast<const uint4*>(kvu + (size_t)(ec).x * 128 + 8 * q16); \
    ga = p_[0]; gb = p_[1]; } while (0)

    int2 c0, c1, c2;
    uint4 g0a, g0b, g1a, g1b;
    if (myCnt > 0) c0 = cp[0];
    if (myCnt > 1) c1 = cp[4];
    if (myCnt > 2) c2 = cp[8];
    if (myCnt > 0) KVG(c0, g0a, g0b);
    if (myCnt > 1) KVG(c1, g1a, g1b);

    for (int j = 0; j < myCnt; ++j) {
        const float eav = __int_as_float(c0.y);
        // k dims: g?a.x(lo,hi), g?a.z, g?b.x, g?b.z ; v dims: .y/.w
        float k0 = __uint_as_float(g0a.x << 16);
        float k1 = __uint_as_float(g0a.x & 0xffff0000u);
        float k2 = __uint_as_float(g0a.z << 16);
        float k3 = __uint_as_float(g0a.z & 0xffff0000u);
        float k4 = __uint_as_float(g0b.x << 16);
        float k5 = __uint_as_float(g0b.x & 0xffff0000u);
        float k6 = __uint_as_float(g0b.z << 16);
        float k7 = __uint_as_float(g0b.z & 0xffff0000u);
        float part = qa.x * k0 + qa.y * k1 + qa.z * k2 + qa.w * k3
                   + qc.x * k4 + qc.y * k5 + qc.z * k6 + qc.w * k7;
        part += __shfl_xor(part, 1);
        float alpha = fmaf(eav, qwe, part) * 0.25f;     // 1/sqrt(16)
        float d = alpha - m;
        if (__any(d > 8.f)) {                           // rare (1st iter + outliers)
            float nm = fmaxf(m, alpha);
            float sc = __expf(m - nm);                  // m=-inf -> 0
            m = nm; d = alpha - m;
            s *= sc; sWE *= sc;
            a0 *= sc; a1 *= sc; a2 *= sc; a3 *= sc;
            a4 *= sc; a5 *= sc; a6 *= sc; a7 *= sc;
        }
        float pv = __expf(d);                           // bounded by e^8
        s += pv;
        sWE = fmaf(pv, eav, sWE);
        float v0 = __uint_as_float(g0a.y << 16);
        float v1 = __uint_as_float(g0a.y & 0xffff0000u);
        float v2 = __uint_as_float(g0a.w << 16);
        float v3 = __uint_as_float(g0a.w & 0xffff0000u);
        float v4 = __uint_as_float(g0b.y << 16);
        float v5 = __uint_as_float(g0b.y & 0xffff0000u);
        float v6 = __uint_as_float(g0b.w << 16);
        float v7 = __uint_as_float(g0b.w & 0xffff0000u);
        a0 = fmaf(pv, v0, a0); a1 = fmaf(pv, v1, a1);
        a2 = fmaf(pv, v2, a2); a3 = fmaf(pv, v3, a3);
        a4 = fmaf(pv, v4, a4); a5 = fmaf(pv, v5, a5);
        a6 = fmaf(pv, v6, a6); a7 = fmaf(pv, v7, a7);
        // rotate queues: csr 3 ahead, gather 2 ahead
        c0 = c1; c1 = c2;
        g0a = g1a; g0b = g1b;
        if (j + 3 < myCnt) c2 = cp[4 * j + 12];
        if (j + 2 < myCnt) KVG(c1, g1a, g1b);
    }

    // merge the four quarter-states: xor 16 then xor 32
#pragma unroll
    for (int mk = 16; mk <= 32; mk <<= 1) {
        float om  = __shfl_xor(m, mk);
        float os  = __shfl_xor(s, mk);
        float oWE = __shfl_xor(sWE, mk);
        float o0 = __shfl_xor(a0, mk), o1 = __shfl_xor(a1, mk);
        float o2 = __shfl_xor(a2, mk), o3 = __shfl_xor(a3, mk);
        float o4 = __shfl_xor(a4, mk), o5 = __shfl_xor(a5, mk);
        float o6 = __shfl_xor(a6, mk), o7 = __shfl_xor(a7, mk);
        float nm = fmaxf(m, om);
        float eS = (s  > 0.f) ? __expf(m  - nm) : 0.f;
        float eO = (os > 0.f) ? __expf(om - nm) : 0.f;
        m = nm;
        s   = s  * eS + os  * eO;
        sWE = sWE * eS + oWE * eO;
        a0 = a0 * eS + o0 * eO; a1 = a1 * eS + o1 * eO;
        a2 = a2 * eS + o2 * eO; a3 = a3 * eS + o3 * eO;
        a4 = a4 * eS + o4 * eO; a5 = a5 * eS + o5 * eO;
        a6 = a6 * eS + o6 * eO; a7 = a7 * eS + o7 * eO;
    }

    if (quad == 0) {
        float inv = 1.0f / fmaxf(s, 1e-16f);
        const float4 s0 = *reinterpret_cast<const float4*>(sb + (size_t)node * 128 + 8 * q16);
        const float4 s1 = *reinterpret_cast<const float4*>(sb + (size_t)node * 128 + 8 * q16 + 4);
        float4 oA, oB;
        oA.x = fmaf(sWE, wa.x, a0) * inv + s0.x;
        oA.y = fmaf(sWE, wa.y, a1) * inv + s0.y;
        oA.z = fmaf(sWE, wa.z, a2) * inv + s0.z;
        oA.w = fmaf(sWE, wa.w, a3) * inv + s0.w;
        oB.x = fmaf(sWE, wc.x, a4) * inv + s1.x;
        oB.y = fmaf(sWE, wc.y, a5) * inv + s1.y;
        oB.z = fmaf(sWE, wc.z, a6) * inv + s1.z;
        oB.w = fmaf(sWE, wc.w, a7) * inv + s1.w;
        *reinterpret_cast<float4*>(heads_cat + (size_t)node * 128 + 8 * q16)     = oA;
        *reinterpret_cast<float4*>(heads_cat + (size_t)node * 128 + 8 * q16 + 4) = oB;
    }
#undef KVG
}

extern "C" void kernel_launch(void* const* d_in, const int* in_sizes, int n_in,
                              void* d_out, int out_size, void* d_ws, size_t ws_size,
                              hipStream_t stream)
{
    const float* x    = (const float*)d_in[0];
    const int*   ei   = (const int*)d_in[1];
    const float* ea   = (const float*)d_in[2];
    const float* Wq   = (const float*)d_in[3];
    const float* bq   = (const float*)d_in[4];
    const float* Wk   = (const float*)d_in[5];
    const float* bk   = (const float*)d_in[6];
    const float* Wv   = (const float*)d_in[7];
    const float* bv   = (const float*)d_in[8];
    const float* We   = (const float*)d_in[9];
    const float* Wsk  = (const float*)d_in[10];
    const float* bsk  = (const float*)d_in[11];
    const float* Wo   = (const float*)d_in[12];
    const float* bo   = (const float*)d_in[13];
    const float* gamma= (const float*)d_in[14];
    const float* beta = (const float*)d_in[15];
    const int N = in_sizes[0] / 128;
    const int E = in_sizes[1] / 2;
    float* out = (float*)d_out;

    char* w = (char*)d_ws;
    float* qarr      = (float*)w; w += (size_t)N * 128 * sizeof(float);
    float* skiparr   = (float*)w; w += (size_t)N * 128 * sizeof(float);
    unsigned short* kv = (unsigned short*)w; w += (size_t)N * 256 * sizeof(unsigned short);
    float* heads_cat = (float*)w; w += (size_t)N * 128 * sizeof(float);
    int*   deg       = (int*)w;   w += ((size_t)N + 16) * sizeof(int);
    int*   offs      = (int*)w;   w += ((size_t)N + 16) * sizeof(int);
    int*   cursor    = (int*)w;   w += ((size_t)N + 16) * sizeof(int);
    int*   csums     = (int*)w;   w += 256 * sizeof(int);
    int2*  csr       = (int2*)w;  w += (size_t)E * sizeof(int2);
    unsigned short* WtH = (unsigned short*)w; w += (size_t)5 * 16384 * sizeof(unsigned short);
    unsigned short* WtL = (unsigned short*)w; w += (size_t)5 * 16384 * sizeof(unsigned short);
    float* bias_cat  = (float*)w; w += 4 * 128 * sizeof(float);

    hipMemsetAsync(deg, 0, (size_t)N * sizeof(int), stream);

    const int cntBlocks = (E + 255) / 256;
    prep_count_kernel<<<5 + cntBlocks, 256, 0, stream>>>(Wq, Wk, Wv, Wsk, Wo, bq, bk, bv, bsk,
                                                         WtH, WtL, bias_cat, ei, deg, E);

    dim3 gProj((N + 63) / 64, 2);
    gemm_proj_kernel<<<gProj, 256, 0, stream>>>(x, WtH, WtL, bias_cat, qarr, skiparr, kv, N);

    const int nChunks = (N + 4095) / 4096;
    scan_part1<<<nChunks, 1024, 0, stream>>>(deg, offs, csums, N);
    scan_part2<<<1, 64, 0, stream>>>(csums, nChunks, offs, N);
    scan_part3<<<nChunks, 1024, 0, stream>>>(offs, csums, cursor, N);

    scatter_kernel<<<(E + 255) / 256, 256, 0, stream>>>(ei, ea, cursor, csr, E);
    agg_kernel<<<(N + 3) / 4, 256, 0, stream>>>(qarr, skiparr, kv, offs, csr, We, heads_cat, N);

    gemm_out_ln_kernel<<<(N + 63) / 64, 256, 0, stream>>>(heads_cat,
                                                          WtH + (size_t)4 * 16384,
                                                          WtL + (size_t)4 * 16384,
                                                          bo, x, gamma, beta, out, N);
}